// Round 1
// baseline (301.990 us; speedup 1.0000x reference)
//
#include <hip/hip_runtime.h>
#include <stdint.h>

#define N 4096
#define NH 8
#define NO 16
#define NF 6

// ---------------- workspace layout (bytes) ----------------
// Wh   : 0         8*4096*16 f32 = 2 MB   [h][n][o]
// es   : 2097152   8*4096 f32             [h][n]
// ed   : 2228224   8*4096 f32             [h][n]
// x2   : 2359296   4096*128 f32           [n][h*16+o]
// Wh2  : 4456448   4096 f32
// ed2  : 4472832   4096 f32
// bits : 4489216   4096*64 u64 = 2 MB     row-major bitmask of adj
#define OFF_WH   0
#define OFF_ES   2097152
#define OFF_ED   2228224
#define OFF_X2   2359296
#define OFF_WH2  4456448
#define OFF_ED2  4472832
#define OFF_BITS 4489216

// ---- kernel 1: Wh = x @ W per head; es/ed = Wh . a halves ----
__global__ __launch_bounds__(256) void k_wh(const float* __restrict__ x,
                                            const float* __restrict__ W,
                                            const float* __restrict__ a,
                                            float* __restrict__ Wh,
                                            float* __restrict__ es,
                                            float* __restrict__ ed) {
    int tid = blockIdx.x * 256 + threadIdx.x;   // 32768 threads: (n,h)
    int n = tid >> 3, h = tid & 7;
    float xf[NF];
#pragma unroll
    for (int f = 0; f < NF; ++f) xf[f] = x[n * NF + f];
    float wh[NO];
#pragma unroll
    for (int o = 0; o < NO; ++o) {
        float s = 0.f;
#pragma unroll
        for (int f = 0; f < NF; ++f) s = fmaf(xf[f], W[(h * NF + f) * NO + o], s);
        wh[o] = s;
    }
    float s1 = 0.f, s2 = 0.f;
#pragma unroll
    for (int o = 0; o < NO; ++o) {
        s1 = fmaf(wh[o], a[h * 32 + o], s1);
        s2 = fmaf(wh[o], a[h * 32 + 16 + o], s2);
    }
    float* dst = Wh + (size_t)((h << 12) + n) * NO;
#pragma unroll
    for (int o = 0; o < NO; ++o) dst[o] = wh[o];
    es[(h << 12) + n] = s1;
    ed[(h << 12) + n] = s2;
}

// ---- kernel 2: pack adjacency to bitmask via ballot ----
__global__ __launch_bounds__(256) void k_bits(const int* __restrict__ adj,
                                              unsigned long long* __restrict__ bits) {
    int lane = threadIdx.x & 63;
    int n = (blockIdx.x << 2) + (threadIdx.x >> 6);   // 1024 blocks * 4 waves
    const int* row = adj + (size_t)n * N;
    for (int w = 0; w < 64; ++w) {
        int v = row[(w << 6) + lane];
        unsigned long long b = __ballot(v != 0);
        if (lane == 0) bits[(size_t)n * 64 + w] = b;
    }
}

// ---- kernel 3: layer-1 masked-softmax attention, 8 heads, O=16 ----
// grid = 8 heads * 64 row-groups; block = 256 (4 waves split m into quarters).
// Lane owns one row n; m is wave-uniform -> Wh/ed come in via scalar loads.
__global__ __launch_bounds__(256) void k_attn1(const float* __restrict__ Wh,
                                               const float* __restrict__ es,
                                               const float* __restrict__ ed,
                                               const uint32_t* __restrict__ bits,
                                               float* __restrict__ x2) {
    int h = blockIdx.x >> 6;
    int rg = blockIdx.x & 63;
    int lane = threadIdx.x & 63;
    int wv = threadIdx.x >> 6;
    int n = (rg << 6) + lane;

    float esn = es[(h << 12) + n];
    float acc[NO];
#pragma unroll
    for (int o = 0; o < NO; ++o) acc[o] = 0.f;
    float den = 0.f;

    const uint32_t* rowbits = bits + (size_t)n * 128;
    int m0u = __builtin_amdgcn_readfirstlane(wv << 10);   // wave's m base, uniform

    for (int mw = 0; mw < 1024; mw += 32) {
        uint32_t wb = rowbits[(m0u + mw) >> 5];
#pragma unroll
        for (int mi = 0; mi < 32; ++mi) {
            int mu = m0u + mw + mi;                        // scalar index
            float edm = ed[(h << 12) + mu];                // s_load
            const float4* whp = (const float4*)(Wh + ((size_t)((h << 12) + mu) << 4));
            float wvec[16];
            *(float4*)&wvec[0]  = whp[0];                  // s_load_dwordx16
            *(float4*)&wvec[4]  = whp[1];
            *(float4*)&wvec[8]  = whp[2];
            *(float4*)&wvec[12] = whp[3];
            float s = esn + edm;
            s = fmaxf(s, 0.2f * s);                        // leaky relu (alpha>0 trick)
            float e = __expf(s);
            e = (wb & (1u << mi)) ? e : 0.f;
            den += e;
#pragma unroll
            for (int o = 0; o < NO; ++o) acc[o] = fmaf(e, wvec[o], acc[o]);
        }
    }

    // combine the 4 wave partials, finalize softmax + ELU, write x2
    __shared__ float red[4][64][17];
#pragma unroll
    for (int o = 0; o < NO; ++o) red[wv][lane][o] = acc[o];
    red[wv][lane][16] = den;
    __syncthreads();

    int r = threadIdx.x & 63, c = threadIdx.x >> 6;        // c: 4 o's each
    float d = red[0][r][16] + red[1][r][16] + red[2][r][16] + red[3][r][16];
    float vals[4];
#pragma unroll
    for (int j = 0; j < 4; ++j) {
        int o = (c << 2) + j;
        float s = red[0][r][o] + red[1][r][o] + red[2][r][o] + red[3][r][o];
        float v = s / d;
        vals[j] = v > 0.f ? v : expm1f(v);                 // jax.nn.elu
    }
    float4* dst = (float4*)(x2 + (size_t)((rg << 6) + r) * 128 + (h << 4) + (c << 2));
    *dst = make_float4(vals[0], vals[1], vals[2], vals[3]);
}

// ---- kernel 4: Wh2 = x2 @ W_out (C=1); ed2 = a_out[1]*Wh2 ----
__global__ __launch_bounds__(256) void k_wh2(const float* __restrict__ x2,
                                             const float* __restrict__ W_out,
                                             const float* __restrict__ a_out,
                                             float* __restrict__ Wh2,
                                             float* __restrict__ ed2) {
    int n = blockIdx.x * 256 + threadIdx.x;
    const float4* xp = (const float4*)(x2 + (size_t)n * 128);
    const float4* wp = (const float4*)W_out;
    float s = 0.f;
#pragma unroll
    for (int k = 0; k < 32; ++k) {
        float4 xv = xp[k], wv = wp[k];
        s = fmaf(xv.x, wv.x, s);
        s = fmaf(xv.y, wv.y, s);
        s = fmaf(xv.z, wv.z, s);
        s = fmaf(xv.w, wv.w, s);
    }
    Wh2[n] = s;
    ed2[n] = s * a_out[1];
}

// ---- kernel 5: layer-2 attention (single scalar head), write d_out ----
// grid = 64 row-groups; block = 1024 (16 waves split m into 256-chunks).
__global__ __launch_bounds__(1024) void k_attn2(const float* __restrict__ Wh2,
                                                const float* __restrict__ ed2,
                                                const float* __restrict__ a_out,
                                                const uint32_t* __restrict__ bits,
                                                float* __restrict__ out) {
    int rg = blockIdx.x;
    int lane = threadIdx.x & 63;
    int wv = threadIdx.x >> 6;        // 0..15
    int n = (rg << 6) + lane;

    float esn = Wh2[n] * a_out[0];
    float num = 0.f, den = 0.f;
    const uint32_t* rowbits = bits + (size_t)n * 128;
    int m0u = __builtin_amdgcn_readfirstlane(wv << 8);    // 256 m's per wave

    for (int mw = 0; mw < 256; mw += 32) {
        uint32_t wb = rowbits[(m0u + mw) >> 5];
#pragma unroll
        for (int mi = 0; mi < 32; ++mi) {
            int mu = m0u + mw + mi;
            float w2 = Wh2[mu];                           // s_load
            float s = esn + ed2[mu];                      // s_load
            s = fmaxf(s, 0.2f * s);
            float e = __expf(s);
            e = (wb & (1u << mi)) ? e : 0.f;
            num = fmaf(e, w2, num);
            den += e;
        }
    }

    __shared__ float rn[16][64], rd[16][64];
    rn[wv][lane] = num;
    rd[wv][lane] = den;
    __syncthreads();
    if (threadIdx.x < 64) {
        int r = threadIdx.x;
        float nn = 0.f, dd = 0.f;
#pragma unroll
        for (int p = 0; p < 16; ++p) { nn += rn[p][r]; dd += rd[p][r]; }
        float v = nn / dd;
        out[(rg << 6) + r] = v > 0.f ? v : expm1f(v);
    }
}

extern "C" void kernel_launch(void* const* d_in, const int* in_sizes, int n_in,
                              void* d_out, int out_size, void* d_ws, size_t ws_size,
                              hipStream_t stream) {
    const float* x     = (const float*)d_in[0];
    const int*   adj   = (const int*)d_in[1];
    const float* W     = (const float*)d_in[2];
    const float* a     = (const float*)d_in[3];
    const float* W_out = (const float*)d_in[4];
    const float* a_out = (const float*)d_in[5];
    float* out = (float*)d_out;

    char* ws = (char*)d_ws;
    float* Wh  = (float*)(ws + OFF_WH);
    float* es  = (float*)(ws + OFF_ES);
    float* ed  = (float*)(ws + OFF_ED);
    float* x2  = (float*)(ws + OFF_X2);
    float* Wh2 = (float*)(ws + OFF_WH2);
    float* ed2 = (float*)(ws + OFF_ED2);
    unsigned long long* bits = (unsigned long long*)(ws + OFF_BITS);

    hipLaunchKernelGGL(k_wh,    dim3(128),  dim3(256),  0, stream, x, W, a, Wh, es, ed);
    hipLaunchKernelGGL(k_bits,  dim3(1024), dim3(256),  0, stream, adj, bits);
    hipLaunchKernelGGL(k_attn1, dim3(512),  dim3(256),  0, stream, Wh, es, ed,
                       (const uint32_t*)bits, x2);
    hipLaunchKernelGGL(k_wh2,   dim3(16),   dim3(256),  0, stream, x2, W_out, a_out, Wh2, ed2);
    hipLaunchKernelGGL(k_attn2, dim3(64),   dim3(1024), 0, stream, Wh2, ed2, a_out,
                       (const uint32_t*)bits, out);
}

// Round 2
// 264.938 us; speedup vs baseline: 1.1399x; 1.1399x over previous
//
#include <hip/hip_runtime.h>
#include <stdint.h>

#define N 4096
#define NH 8
#define NO 16
#define NF 6

// ---------------- workspace layout (bytes) ----------------
#define OFF_WH   0          // 8*4096*16 f32 = 2 MB   [h][n][o]
#define OFF_ES   2097152    // 8*4096 f32             [h][n]
#define OFF_ED   2228224    // 8*4096 f32             [h][n]
#define OFF_X2   2359296    // 4096*128 f32           [n][h*16+o]
#define OFF_WH2  4456448    // 4096 f32
#define OFF_ED2  4472832    // 4096 f32
#define OFF_BITS 4489216    // 4096*64 u64 = 2 MB     row-major bitmask of adj

// ---- kernel 1: Wh = x @ W per head; es/ed = Wh . a halves ----
__global__ __launch_bounds__(256) void k_wh(const float* __restrict__ x,
                                            const float* __restrict__ W,
                                            const float* __restrict__ a,
                                            float* __restrict__ Wh,
                                            float* __restrict__ es,
                                            float* __restrict__ ed) {
    int tid = blockIdx.x * 256 + threadIdx.x;   // 32768 threads: (n,h)
    int n = tid >> 3, h = tid & 7;
    float xf[NF];
#pragma unroll
    for (int f = 0; f < NF; ++f) xf[f] = x[n * NF + f];
    float wh[NO];
#pragma unroll
    for (int o = 0; o < NO; ++o) {
        float s = 0.f;
#pragma unroll
        for (int f = 0; f < NF; ++f) s = fmaf(xf[f], W[(h * NF + f) * NO + o], s);
        wh[o] = s;
    }
    float s1 = 0.f, s2 = 0.f;
#pragma unroll
    for (int o = 0; o < NO; ++o) {
        s1 = fmaf(wh[o], a[h * 32 + o], s1);
        s2 = fmaf(wh[o], a[h * 32 + 16 + o], s2);
    }
    float* dst = Wh + (size_t)((h << 12) + n) * NO;
#pragma unroll
    for (int o = 0; o < NO; ++o) dst[o] = wh[o];
    es[(h << 12) + n] = s1;
    ed[(h << 12) + n] = s2;
}

// ---- kernel 2: pack adjacency to bitmask via ballot (HBM-bound, ~10us) ----
__global__ __launch_bounds__(256) void k_bits(const int* __restrict__ adj,
                                              unsigned long long* __restrict__ bits) {
    int lane = threadIdx.x & 63;
    int n = (blockIdx.x << 2) + (threadIdx.x >> 6);   // 1024 blocks * 4 waves
    const int* row = adj + (size_t)n * N;
#pragma unroll 4
    for (int w = 0; w < 64; ++w) {
        int v = row[(w << 6) + lane];
        unsigned long long b = __ballot(v != 0);
        if (lane == 0) bits[(size_t)n * 64 + w] = b;
    }
}

// ---- kernel 3: layer-1 masked-softmax attention ----
// grid = 8 heads * 64 row-groups; block = 1024 (16 waves x 256 m's each)
// -> 2 blocks/CU * 16 waves = 32 waves/CU = full occupancy.
// Lane owns one row n; m is wave-uniform -> Wh/ed come in via scalar loads.
// Cross-wave combine via LDS float atomics (4.4 KB, keeps 2 blocks/CU).
__global__ __launch_bounds__(1024) void k_attn1(const float* __restrict__ Wh,
                                                const float* __restrict__ es,
                                                const float* __restrict__ ed,
                                                const uint32_t* __restrict__ bits,
                                                float* __restrict__ x2) {
    int h = blockIdx.x >> 6;
    int rg = blockIdx.x & 63;
    int lane = threadIdx.x & 63;
    int wv = threadIdx.x >> 6;          // 0..15
    int n = (rg << 6) + lane;

    __shared__ float red[64][17];       // [row][o 0..15, den]
    for (int i = threadIdx.x; i < 64 * 17; i += 1024) ((float*)red)[i] = 0.f;
    __syncthreads();

    float esn = es[(h << 12) + n];
    float acc[NO];
#pragma unroll
    for (int o = 0; o < NO; ++o) acc[o] = 0.f;
    float den = 0.f;

    const uint32_t* rowbits = bits + (size_t)n * 128;
    int m0u = __builtin_amdgcn_readfirstlane(wv << 8);   // wave's m base, uniform

    for (int mw = 0; mw < 256; mw += 32) {
        uint32_t wb = rowbits[(m0u + mw) >> 5];
#pragma unroll
        for (int mi = 0; mi < 32; ++mi) {
            int mu = m0u + mw + mi;                      // wave-uniform index
            float edm = ed[(h << 12) + mu];              // s_load
            const float4* whp = (const float4*)(Wh + ((size_t)((h << 12) + mu) << 4));
            float wvec[16];
            *(float4*)&wvec[0]  = whp[0];                // s_load_dwordx16
            *(float4*)&wvec[4]  = whp[1];
            *(float4*)&wvec[8]  = whp[2];
            *(float4*)&wvec[12] = whp[3];
            float s = esn + edm;
            s = fmaxf(s, 0.2f * s);                      // leaky relu
            float e = __expf(s);
            e = (wb & (1u << mi)) ? e : 0.f;
            den += e;
#pragma unroll
            for (int o = 0; o < NO; ++o) acc[o] = fmaf(e, wvec[o], acc[o]);
        }
    }

    // cross-wave combine: ds_add_f32 into red[row][*]
#pragma unroll
    for (int o = 0; o < NO; ++o) atomicAdd(&red[lane][o], acc[o]);
    atomicAdd(&red[lane][16], den);
    __syncthreads();

    // finalize: thread -> (row r2, col c2); consecutive tid = consecutive c2
    int r2 = threadIdx.x >> 4, c2 = threadIdx.x & 15;
    float d = red[r2][16];
    float v = red[r2][c2] / d;
    v = v > 0.f ? v : expm1f(v);                         // jax.nn.elu
    x2[(size_t)((rg << 6) + r2) * 128 + (h << 4) + c2] = v;
}

// ---- kernel 4: Wh2 = x2 @ W_out (C=1); ed2 = a_out[1]*Wh2 ----
__global__ __launch_bounds__(256) void k_wh2(const float* __restrict__ x2,
                                             const float* __restrict__ W_out,
                                             const float* __restrict__ a_out,
                                             float* __restrict__ Wh2,
                                             float* __restrict__ ed2) {
    int n = blockIdx.x * 256 + threadIdx.x;
    const float4* xp = (const float4*)(x2 + (size_t)n * 128);
    const float4* wp = (const float4*)W_out;
    float s = 0.f;
#pragma unroll
    for (int k = 0; k < 32; ++k) {
        float4 xv = xp[k], wv = wp[k];
        s = fmaf(xv.x, wv.x, s);
        s = fmaf(xv.y, wv.y, s);
        s = fmaf(xv.z, wv.z, s);
        s = fmaf(xv.w, wv.w, s);
    }
    Wh2[n] = s;
    ed2[n] = s * a_out[1];
}

// ---- kernel 5: layer-2 attention, wave-per-row / lane-per-m ----
// grid = 1024 blocks * 256 (4 waves = 4 rows/block). Lanes split m:
// coalesced vector loads of Wh2/ed2, uniform u64 mask word per iter,
// butterfly shuffle reduce.
__global__ __launch_bounds__(256) void k_attn2(const float* __restrict__ Wh2,
                                               const float* __restrict__ ed2,
                                               const float* __restrict__ a_out,
                                               const unsigned long long* __restrict__ bits,
                                               float* __restrict__ out) {
    int lane = threadIdx.x & 63;
    int wv = threadIdx.x >> 6;
    int n = (blockIdx.x << 2) + wv;

    float esn = Wh2[n] * a_out[0];
    float num = 0.f, den = 0.f;
    const unsigned long long* rowbits = bits + (size_t)n * 64;

#pragma unroll 4
    for (int it = 0; it < 64; ++it) {
        int m = (it << 6) + lane;
        float w2 = Wh2[m];                               // coalesced
        float s = esn + ed2[m];                          // coalesced
        unsigned long long wb = rowbits[it];             // uniform s_load
        s = fmaxf(s, 0.2f * s);
        float e = __expf(s);
        e = ((wb >> lane) & 1ull) ? e : 0.f;
        num = fmaf(e, w2, num);
        den += e;
    }
#pragma unroll
    for (int off = 32; off > 0; off >>= 1) {
        num += __shfl_xor(num, off);
        den += __shfl_xor(den, off);
    }
    if (lane == 0) {
        float v = num / den;
        out[n] = v > 0.f ? v : expm1f(v);
    }
}

extern "C" void kernel_launch(void* const* d_in, const int* in_sizes, int n_in,
                              void* d_out, int out_size, void* d_ws, size_t ws_size,
                              hipStream_t stream) {
    const float* x     = (const float*)d_in[0];
    const int*   adj   = (const int*)d_in[1];
    const float* W     = (const float*)d_in[2];
    const float* a     = (const float*)d_in[3];
    const float* W_out = (const float*)d_in[4];
    const float* a_out = (const float*)d_in[5];
    float* out = (float*)d_out;

    char* ws = (char*)d_ws;
    float* Wh  = (float*)(ws + OFF_WH);
    float* es  = (float*)(ws + OFF_ES);
    float* ed  = (float*)(ws + OFF_ED);
    float* x2  = (float*)(ws + OFF_X2);
    float* Wh2 = (float*)(ws + OFF_WH2);
    float* ed2 = (float*)(ws + OFF_ED2);
    unsigned long long* bits = (unsigned long long*)(ws + OFF_BITS);

    hipLaunchKernelGGL(k_wh,    dim3(128),  dim3(256),  0, stream, x, W, a, Wh, es, ed);
    hipLaunchKernelGGL(k_bits,  dim3(1024), dim3(256),  0, stream, adj, bits);
    hipLaunchKernelGGL(k_attn1, dim3(512),  dim3(1024), 0, stream, Wh, es, ed,
                       (const uint32_t*)bits, x2);
    hipLaunchKernelGGL(k_wh2,   dim3(16),   dim3(256),  0, stream, x2, W_out, a_out, Wh2, ed2);
    hipLaunchKernelGGL(k_attn2, dim3(1024), dim3(256),  0, stream, Wh2, ed2, a_out,
                       bits, out);
}

// Round 4
// 206.899 us; speedup vs baseline: 1.4596x; 1.2805x over previous
//
#include <hip/hip_runtime.h>
#include <stdint.h>

#define N 4096
#define NH 8
#define NO 16
#define NF 6

typedef _Float16 half8 __attribute__((ext_vector_type(8)));
typedef float floatx4 __attribute__((ext_vector_type(4)));

// ---------------- workspace layout (bytes) ----------------
#define OFF_WHF  0          // 8*4096*16 fp16 = 1 MB, B-fragment order [h][mtile][lane][j]
#define OFF_ES   2097152    // 8*4096 f32  [h][n]
#define OFF_ED   2228224    // 8*4096 f32  [h][n]
#define OFF_X2   2359296    // 4096*128 f32 [n][h*16+o]
#define OFF_WH2  4456448    // 4096 f32
#define OFF_ED2  4472832    // 4096 f32
#define OFF_BITS 4489216    // TRANSPOSED bitmask: u64 [64 words][4096 rows] = 2 MB

// ---- kernel 1: Wh = x@W per head -> fp16 B-frag layout; es/ed = Wh.a halves ----
__global__ __launch_bounds__(256) void k_wh(const float* __restrict__ x,
                                            const float* __restrict__ W,
                                            const float* __restrict__ a,
                                            _Float16* __restrict__ Whf,
                                            float* __restrict__ es,
                                            float* __restrict__ ed) {
    int tid = blockIdx.x * 256 + threadIdx.x;   // 32768 threads: (n,h)
    int n = tid >> 3, h = tid & 7;
    float xf[NF];
#pragma unroll
    for (int f = 0; f < NF; ++f) xf[f] = x[n * NF + f];
    float wh[NO];
#pragma unroll
    for (int o = 0; o < NO; ++o) {
        float s = 0.f;
#pragma unroll
        for (int f = 0; f < NF; ++f) s = fmaf(xf[f], W[(h * NF + f) * NO + o], s);
        wh[o] = s;
    }
    float s1 = 0.f, s2 = 0.f;
#pragma unroll
    for (int o = 0; o < NO; ++o) {
        s1 = fmaf(wh[o], a[h * 32 + o], s1);
        s2 = fmaf(wh[o], a[h * 32 + 16 + o], s2);
    }
    // B-fragment scatter: for m-tile of 32, lane = q*16+o holds B[k=q*8+j][o],
    // i.e. element Wh[m0+q*8+j][o].  n -> tile=n>>5, q=(n>>3)&3, j=n&7.
    int tile = n >> 5, q = (n >> 3) & 3, j = n & 7;
    _Float16* base = Whf + ((size_t)((h << 7) + tile) << 9) + j;
#pragma unroll
    for (int o = 0; o < NO; ++o) base[(size_t)(((q << 4) + o) << 3)] = (_Float16)wh[o];
    es[(h << 12) + n] = s1;
    ed[(h << 12) + n] = s2;
}

// ---- kernel 2: pack adjacency to TRANSPOSED bitmask [word][row] ----
__global__ __launch_bounds__(256) void k_bits(const int* __restrict__ adj,
                                              unsigned long long* __restrict__ bits) {
    int lane = threadIdx.x & 63;
    int n = (blockIdx.x << 2) + (threadIdx.x >> 6);   // 1024 blocks * 4 waves
    const int* row = adj + (size_t)n * N;
#pragma unroll 4
    for (int w = 0; w < 64; ++w) {
        int v = row[(w << 6) + lane];
        unsigned long long b = __ballot(v != 0);
        if (lane == 0) bits[((size_t)w << 12) + n] = b;
    }
}

// ---- kernel 3: layer-1 attention via fp16 MFMA 16x16x32 ----
// grid = 8 heads * 64 row-groups (64 rows each); block = 256 = 4 waves,
// wave wv covers m in [wv*1024, wv*1024+1024) in 32-m steps.
// Per step: 4 row-tiles of 16 -> 4 MFMAs; P (=masked exp scores) computed
// per-lane directly in A-fragment layout A[m=lane&15][k=quad*8+j] (m120).
// C/D layout: col=lane&15(=o), row=quad*4+reg (m89).
__global__ __launch_bounds__(256) void k_attn1(const _Float16* __restrict__ Whf,
                                               const float* __restrict__ es,
                                               const float* __restrict__ ed,
                                               const uint32_t* __restrict__ bits,
                                               float* __restrict__ x2) {
    int h = blockIdx.x >> 6;
    int rg = blockIdx.x & 63;
    int lane = threadIdx.x & 63;
    int wv = threadIdx.x >> 6;
    int l15 = lane & 15, q = lane >> 4, qb = q << 3;
    int rowb = rg << 6;

    __shared__ float red[64][17];       // [row][o 0..15, den]
    for (int i = threadIdx.x; i < 64 * 17; i += 256) ((float*)red)[i] = 0.f;
    __syncthreads();

    float esn[4];
    int rowoff[4];
#pragma unroll
    for (int t = 0; t < 4; ++t) {
        esn[t] = es[(h << 12) + rowb + (t << 4) + l15];
        rowoff[t] = (rowb + (t << 4) + l15) << 1;     // u32 index into bitsT column
    }

    floatx4 acc[4];
#pragma unroll
    for (int t = 0; t < 4; ++t) { acc[t][0]=0.f; acc[t][1]=0.f; acc[t][2]=0.f; acc[t][3]=0.f; }
    float den[4] = {0.f, 0.f, 0.f, 0.f};

    const float* edh = ed + (h << 12);

    for (int step = 0; step < 32; ++step) {
        int m0 = (wv << 10) + (step << 5);
        // ed for this lane's 8 k's (two float4, 16-lane broadcast)
        const floatx4* edp = (const floatx4*)(edh + m0 + qb);
        floatx4 ea = edp[0], eb = edp[1];
        float edj[8] = {ea[0],ea[1],ea[2],ea[3],eb[0],eb[1],eb[2],eb[3]};
        // B fragment: coalesced 16B/lane
        half8 bfrag = *(const half8*)(Whf + ((size_t)((h << 7) + (m0 >> 5)) << 9) + (lane << 3));
        // bitsT u32 word base for this 32-m window
        int wbase = ((m0 >> 6) << 13) + ((m0 >> 5) & 1);
#pragma unroll
        for (int t = 0; t < 4; ++t) {
            uint32_t w = bits[wbase + rowoff[t]] >> qb;   // this lane's 8 mask bits
            float ev[8];
#pragma unroll
            for (int j = 0; j < 8; ++j) {
                float s = esn[t] + edj[j];
                s = fmaxf(s, 0.2f * s);                   // leaky relu
                float e = __expf(s);
                e = (w & (1u << j)) ? e : 0.f;
                ev[j] = e;
                den[t] += e;
            }
            half8 afrag;
#pragma unroll
            for (int j = 0; j < 8; ++j) afrag[j] = (_Float16)ev[j];
            acc[t] = __builtin_amdgcn_mfma_f32_16x16x32_f16(afrag, bfrag, acc[t], 0, 0, 0);
        }
    }

    // combine partials (4 waves, m-split) via LDS atomics
#pragma unroll
    for (int t = 0; t < 4; ++t) {
        atomicAdd(&red[(t << 4) + l15][16], den[t]);
#pragma unroll
        for (int r = 0; r < 4; ++r)
            atomicAdd(&red[(t << 4) + (q << 2) + r][l15], acc[t][r]);
    }
    __syncthreads();

    for (int i = threadIdx.x; i < 1024; i += 256) {
        int r2 = i >> 4, c2 = i & 15;
        float v = red[r2][c2] / red[r2][16];
        v = v > 0.f ? v : expm1f(v);                     // jax.nn.elu
        x2[(size_t)(rowb + r2) * 128 + (h << 4) + c2] = v;
    }
}

// ---- kernel 4: Wh2 = x2 @ W_out (C=1), wave per row ----
__global__ __launch_bounds__(256) void k_wh2(const float* __restrict__ x2,
                                             const float* __restrict__ W_out,
                                             const float* __restrict__ a_out,
                                             float* __restrict__ Wh2,
                                             float* __restrict__ ed2) {
    int lane = threadIdx.x & 63;
    int n = (blockIdx.x << 2) + (threadIdx.x >> 6);
    const float2* xp = (const float2*)(x2 + (size_t)n * 128);
    const float2* wp = (const float2*)W_out;
    float2 xv = xp[lane], wv2 = wp[lane];
    float s = fmaf(xv.x, wv2.x, xv.y * wv2.y);
#pragma unroll
    for (int off = 32; off; off >>= 1) s += __shfl_xor(s, off);
    if (lane == 0) { Wh2[n] = s; ed2[n] = s * a_out[1]; }
}

// ---- kernel 5: layer-2 attention, block per row, 4 waves split m ----
__global__ __launch_bounds__(256) void k_attn2(const float* __restrict__ Wh2,
                                               const float* __restrict__ ed2,
                                               const float* __restrict__ a_out,
                                               const unsigned long long* __restrict__ bits,
                                               float* __restrict__ out) {
    int n = blockIdx.x;
    int lane = threadIdx.x & 63;
    int wv = threadIdx.x >> 6;
    float esn = Wh2[n] * a_out[0];
    float num = 0.f, den = 0.f;
#pragma unroll
    for (int it = 0; it < 16; ++it) {
        int w = (wv << 4) + it;
        int m = (w << 6) + lane;
        float w2 = Wh2[m];                               // coalesced
        float s = esn + ed2[m];                          // coalesced
        unsigned long long wb = bits[((size_t)w << 12) + n];  // uniform s_load
        s = fmaxf(s, 0.2f * s);
        float e = __expf(s);
        e = ((wb >> lane) & 1ull) ? e : 0.f;
        num = fmaf(e, w2, num);
        den += e;
    }
#pragma unroll
    for (int off = 32; off; off >>= 1) {
        num += __shfl_xor(num, off);
        den += __shfl_xor(den, off);
    }
    __shared__ float rn[4], rd[4];
    if (lane == 0) { rn[wv] = num; rd[wv] = den; }
    __syncthreads();
    if (threadIdx.x == 0) {
        float nn = rn[0] + rn[1] + rn[2] + rn[3];
        float dd = rd[0] + rd[1] + rd[2] + rd[3];
        float v = nn / dd;
        out[n] = v > 0.f ? v : expm1f(v);
    }
}

extern "C" void kernel_launch(void* const* d_in, const int* in_sizes, int n_in,
                              void* d_out, int out_size, void* d_ws, size_t ws_size,
                              hipStream_t stream) {
    const float* x     = (const float*)d_in[0];
    const int*   adj   = (const int*)d_in[1];
    const float* W     = (const float*)d_in[2];
    const float* a     = (const float*)d_in[3];
    const float* W_out = (const float*)d_in[4];
    const float* a_out = (const float*)d_in[5];
    float* out = (float*)d_out;

    char* ws = (char*)d_ws;
    _Float16* Whf = (_Float16*)(ws + OFF_WHF);
    float* es  = (float*)(ws + OFF_ES);
    float* ed  = (float*)(ws + OFF_ED);
    float* x2  = (float*)(ws + OFF_X2);
    float* Wh2 = (float*)(ws + OFF_WH2);
    float* ed2 = (float*)(ws + OFF_ED2);
    unsigned long long* bits = (unsigned long long*)(ws + OFF_BITS);

    hipLaunchKernelGGL(k_wh,    dim3(128),  dim3(256), 0, stream, x, W, a, Whf, es, ed);
    hipLaunchKernelGGL(k_bits,  dim3(1024), dim3(256), 0, stream, adj, bits);
    hipLaunchKernelGGL(k_attn1, dim3(512),  dim3(256), 0, stream, Whf, es, ed,
                       (const uint32_t*)bits, x2);
    hipLaunchKernelGGL(k_wh2,   dim3(1024), dim3(256), 0, stream, x2, W_out, a_out, Wh2, ed2);
    hipLaunchKernelGGL(k_attn2, dim3(4096), dim3(256), 0, stream, Wh2, ed2, a_out,
                       bits, out);
}